// Round 3
// baseline (457.564 us; speedup 1.0000x reference)
//
#include <hip/hip_runtime.h>
#include <hip/hip_bf16.h>
#include <math.h>

// ---------------------------------------------------------------------------
// DistributedMoE forward, MI355X — R3: conflict-free lane=column conv
// structure + ic-split for occupancy + pre-transposed weights.
// One expert per sample (softmax over one dispatched element == 1).
//
// out (fp32): final[256,10] @0, balanced[256,8] @2560, D[256,8] @4608
// ---------------------------------------------------------------------------

#define BN_RS (1.0f / sqrtf(1.00001f))

// ws byte offsets
#define WS_TFP    0          // f32[256][4][32][2] trunk partial sums
#define WS_TK     262144     // i32[512]
#define WS_CHOSEN 264192     // i32[256]
#define WS_FEATG  265216     // f32[256*128]
#define WS_P1G    396288     // f32[256][32][16][16]
#define WS_P2G    8784896    // f32[256][64][8][8]
#define WS_TW2T   12979200   // f32[32ic][9][32oc]
#define WS_EW2T   13016064   // f32[8][32ic][9][64oc]
#define WS_EW3T   13605888   // f32[8][64ic][9][128oc]

// =================== prep: weight transposes to [ic][k][oc] ================
__global__ __launch_bounds__(256) void prep_kernel(
    const float* __restrict__ tw2, const float* __restrict__ ew2,
    const float* __restrict__ ew3, float* __restrict__ tw2t,
    float* __restrict__ ew2t, float* __restrict__ ew3t)
{
  const int j = blockIdx.x * 256 + threadIdx.x;
  if (j < 9216) {
    int ic = j / 288, rem = j % 288, k = rem / 32, oc = rem % 32;
    tw2t[j] = tw2[oc*288 + ic*9 + k];
  } else if (j < 156672) {
    int jj = j - 9216;
    int e = jj / 18432, r2 = jj % 18432, ic = r2 / 576, r3 = r2 % 576;
    int k = r3 / 64, oc = r3 % 64;
    ew2t[jj] = ew2[e*18432 + oc*288 + ic*9 + k];
  } else if (j < 746496) {
    int jj = j - 156672;
    int e = jj / 73728, r2 = jj % 73728, ic = r2 / 1152, r3 = r2 % 1152;
    int k = r3 / 128, oc = r3 % 128;
    ew3t[jj] = ew3[e*73728 + oc*576 + ic*9 + k];
  }
}

// ======================= trunk: conv1+conv2+pool+avg =======================
// grid 1024 = sample*4 + slab(8 conv rows); 256 thr.
// conv1: thread = (ocg 8 x 4oc) x (col 32).  conv2: thread = (ocg 8 x 4oc) x
// (ih ic-half) x (cp 16 col-pairs); acc[4oc][8rows][2cols]; ic-split exchange.
#define T_SA1 0        // conv1 out [32][10][34], data col d at d+1
#define T_SX  10880    // x slab [3][12][34] (phase 1)
#define T_SW1 12104    // 864 (phase 1)
#define T_WD  10880    // w dbuf 2 x [2part][4icl][9][32oc] = 2x2304 (phase 2)
#define T_S1  15488
#define T_O1  15520
#define T_S2  15552
#define T_O2  15584
__global__ __launch_bounds__(256) void trunk_kernel(
    const float* __restrict__ x, const float* __restrict__ tw1,
    const float* __restrict__ tg1, const float* __restrict__ tb1,
    const float* __restrict__ tw2t, const float* __restrict__ tg2,
    const float* __restrict__ tb2, float* __restrict__ tfp)
{
  __shared__ __align__(16) float sm[15616];
  const int t = threadIdx.x;
  const int b = blockIdx.x >> 2, slab = blockIdx.x & 3;
  const int r0 = slab * 8;

  // ---- stage x slab + conv1 weights + bn + sa1 col pads ----
  for (int j = t; j < 1224; j += 256) {
    int ic = j / 408, rr2 = (j % 408) / 34, col = j % 34;
    int gy = r0 - 2 + rr2, gx = col - 1;
    float v = 0.f;
    if (gy >= 0 && gy < 32 && gx >= 0 && gx < 32) v = x[b*3072 + ic*1024 + gy*32 + gx];
    sm[T_SX + j] = v;
  }
  for (int j = t; j < 864; j += 256) sm[T_SW1 + j] = tw1[j];
  if (t < 32) {
    sm[T_S1 + t] = tg1[t]*BN_RS; sm[T_O1 + t] = tb1[t];
    sm[T_S2 + t] = tg2[t]*BN_RS; sm[T_O2 + t] = tb2[t];
  }
  for (int j = t; j < 640; j += 256) {
    int ic = j / 20, rr = (j % 20) / 2, side = j & 1;
    sm[T_SA1 + ic*340 + rr*34 + side*33] = 0.f;
  }
  __syncthreads();

  // ---- conv1: 3->32, rows r0-1..r0+8, bn+relu -> sa1 ----
  {
    const int g1 = t >> 5, c = t & 31;
    float a1[4][10];
    #pragma unroll
    for (int o = 0; o < 4; ++o)
      #pragma unroll
      for (int rr = 0; rr < 10; ++rr) a1[o][rr] = 0.f;
    for (int ic = 0; ic < 3; ++ic) {
      float w[4][9];
      #pragma unroll
      for (int o = 0; o < 4; ++o)
        #pragma unroll
        for (int k = 0; k < 9; ++k) w[o][k] = sm[T_SW1 + (4*g1+o)*27 + ic*9 + k];
      const float* sx0 = &sm[T_SX + ic*408 + c];
      float p00 = sx0[0],  p01 = sx0[1],  p02 = sx0[2];
      float p10 = sx0[34], p11 = sx0[35], p12 = sx0[36];
      #pragma unroll
      for (int rr = 0; rr < 10; ++rr) {
        float p20 = sx0[(rr+2)*34], p21 = sx0[(rr+2)*34+1], p22 = sx0[(rr+2)*34+2];
        #pragma unroll
        for (int o = 0; o < 4; ++o) {
          float a = a1[o][rr];
          a = fmaf(w[o][0], p00, a); a = fmaf(w[o][1], p01, a); a = fmaf(w[o][2], p02, a);
          a = fmaf(w[o][3], p10, a); a = fmaf(w[o][4], p11, a); a = fmaf(w[o][5], p12, a);
          a = fmaf(w[o][6], p20, a); a = fmaf(w[o][7], p21, a); a = fmaf(w[o][8], p22, a);
          a1[o][rr] = a;
        }
        p00 = p10; p01 = p11; p02 = p12;
        p10 = p20; p11 = p21; p12 = p22;
      }
    }
    #pragma unroll
    for (int o = 0; o < 4; ++o) {
      const int oc = 4*g1 + o;
      const float s = sm[T_S1 + oc], bo = sm[T_O1 + oc];
      #pragma unroll
      for (int rr = 0; rr < 10; ++rr) {
        const int ar = r0 - 1 + rr;
        float v = 0.f;
        if (ar >= 0 && ar < 32) v = fmaxf(fmaf(a1[o][rr], s, bo), 0.f);
        sm[T_SA1 + oc*340 + rr*34 + c + 1] = v;
      }
    }
  }
  __syncthreads();

  // ---- stage w2 chunk 0 (parts: ih0 ics 0..3, ih1 ics 16..19) ----
  for (int jj = t; jj < 2304; jj += 256) {
    int part = jj / 1152, r = jj % 1152;
    sm[T_WD + jj] = tw2t[(16*part)*288 + r];
  }
  __syncthreads();

  // ---- conv2: 32->32, ic-split halves, 4 chunks x 4 icl ----
  const int ocg = t >> 5, ih = (t >> 4) & 1, cp = t & 15;
  float acc[4][8][2];
  #pragma unroll
  for (int o = 0; o < 4; ++o)
    #pragma unroll
    for (int r = 0; r < 8; ++r) { acc[o][r][0] = 0.f; acc[o][r][1] = 0.f; }

  for (int cc = 0; cc < 4; ++cc) {
    if (cc > 0) __syncthreads();
    if (cc < 3) {
      const int buf = (cc + 1) & 1;
      for (int jj = t; jj < 2304; jj += 256) {
        int part = jj / 1152, r = jj % 1152;
        sm[T_WD + buf*2304 + jj] = tw2t[(16*part + 4*(cc+1))*288 + r];
      }
    }
    const float* wb = &sm[T_WD + (cc & 1)*2304 + ih*1152];
    #pragma unroll
    for (int icl = 0; icl < 4; ++icl) {
      const int ic = 16*ih + 4*cc + icl;
      float w[4][9];
      #pragma unroll
      for (int k = 0; k < 9; ++k) {
        float4 wv = *(const float4*)&wb[icl*288 + k*32 + 4*ocg];
        w[0][k] = wv.x; w[1][k] = wv.y; w[2][k] = wv.z; w[3][k] = wv.w;
      }
      const float* src = &sm[T_SA1 + ic*340 + 2*cp];
      #pragma unroll
      for (int rr = 0; rr < 10; ++rr) {
        float2 va = *(const float2*)&src[rr*34];
        float2 vb = *(const float2*)&src[rr*34 + 2];
        const float iv0 = va.x, iv1 = va.y, iv2 = vb.x, iv3 = vb.y;
        #pragma unroll
        for (int o = 0; o < 8; ++o) {
          const int ky = rr - o;
          if (ky < 0 || ky > 2) continue;
          #pragma unroll
          for (int oo = 0; oo < 4; ++oo) {
            acc[oo][o][0] = fmaf(w[oo][ky*3+0], iv0, acc[oo][o][0]);
            acc[oo][o][1] = fmaf(w[oo][ky*3+0], iv1, acc[oo][o][1]);
            acc[oo][o][0] = fmaf(w[oo][ky*3+1], iv1, acc[oo][o][0]);
            acc[oo][o][1] = fmaf(w[oo][ky*3+1], iv2, acc[oo][o][1]);
            acc[oo][o][0] = fmaf(w[oo][ky*3+2], iv2, acc[oo][o][0]);
            acc[oo][o][1] = fmaf(w[oo][ky*3+2], iv3, acc[oo][o][1]);
          }
        }
      }
    }
  }

  // ---- ic-split exchange (into dead sa1 region, slot stride 65) ----
  __syncthreads();
  const int slot = ocg*16 + cp;
  if (ih == 1) {
    #pragma unroll
    for (int o = 0; o < 4; ++o)
      #pragma unroll
      for (int r = 0; r < 8; ++r) {
        sm[slot*65 + o*16 + r*2 + 0] = acc[o][r][0];
        sm[slot*65 + o*16 + r*2 + 1] = acc[o][r][1];
      }
  }
  __syncthreads();
  if (ih == 0) {
    #pragma unroll
    for (int o = 0; o < 4; ++o) {
      const int oc = 4*ocg + o;
      const float s = sm[T_S2 + oc], bo = sm[T_O2 + oc];
      float ssum = 0.f;
      #pragma unroll
      for (int pr = 0; pr < 4; ++pr) {
        float c00 = acc[o][2*pr][0]   + sm[slot*65 + o*16 + (2*pr)*2 + 0];
        float c01 = acc[o][2*pr][1]   + sm[slot*65 + o*16 + (2*pr)*2 + 1];
        float c10 = acc[o][2*pr+1][0] + sm[slot*65 + o*16 + (2*pr+1)*2 + 0];
        float c11 = acc[o][2*pr+1][1] + sm[slot*65 + o*16 + (2*pr+1)*2 + 1];
        float v0 = fmaxf(fmaf(c00, s, bo), 0.f);
        float v1 = fmaxf(fmaf(c01, s, bo), 0.f);
        float v2 = fmaxf(fmaf(c10, s, bo), 0.f);
        float v3 = fmaxf(fmaf(c11, s, bo), 0.f);
        ssum += fmaxf(fmaxf(v0, v1), fmaxf(v2, v3));
      }
      ssum += __shfl_xor(ssum, 1);
      ssum += __shfl_xor(ssum, 2);
      ssum += __shfl_xor(ssum, 4);
      if ((t & 7) == 0) {
        const int qx = (t >> 3) & 1;
        tfp[b*256 + slab*64 + oc*2 + qx] = ssum;
      }
    }
  }
}

// ============================== gate + top2 ================================
__global__ __launch_bounds__(64) void gate_kernel(
    const float* __restrict__ tfp, const float* __restrict__ tfw, const float* __restrict__ tfb,
    const float* __restrict__ gw1, const float* __restrict__ gb1,
    const float* __restrict__ gw2, const float* __restrict__ gb2,
    float* __restrict__ outBal, int* __restrict__ tk)
{
  __shared__ float feat[128], rf[64], g1[32], bal[8];
  const int b = blockIdx.x, t = threadIdx.x;
  #pragma unroll
  for (int h = 0; h < 2; ++h) {
    const int f = t + 64*h;
    const int oc = f >> 2, qy = (f >> 1) & 1, qx = f & 1;
    feat[f] = (tfp[b*256 + (2*qy)*64 + oc*2 + qx] +
               tfp[b*256 + (2*qy+1)*64 + oc*2 + qx]) * (1.f/64.f);
  }
  __syncthreads();
  {
    float a = tfb[t];
    const float4* wp = (const float4*)&tfw[t*128];
    #pragma unroll 8
    for (int i4 = 0; i4 < 32; ++i4) {
      float4 wv = wp[i4];
      a = fmaf(wv.x, feat[4*i4], a);   a = fmaf(wv.y, feat[4*i4+1], a);
      a = fmaf(wv.z, feat[4*i4+2], a); a = fmaf(wv.w, feat[4*i4+3], a);
    }
    rf[t] = fmaxf(a, 0.f);
  }
  __syncthreads();
  if (t < 32) {
    float a = gb1[t];
    const float4* wp = (const float4*)&gw1[t*64];
    #pragma unroll
    for (int i4 = 0; i4 < 16; ++i4) {
      float4 wv = wp[i4];
      a = fmaf(wv.x, rf[4*i4], a);   a = fmaf(wv.y, rf[4*i4+1], a);
      a = fmaf(wv.z, rf[4*i4+2], a); a = fmaf(wv.w, rf[4*i4+3], a);
    }
    g1[t] = fmaxf(a, 0.f);
  }
  __syncthreads();
  if (t < 8) {
    float a = gb2[t];
    const float4* wp = (const float4*)&gw2[t*32];
    #pragma unroll
    for (int i4 = 0; i4 < 8; ++i4) {
      float4 wv = wp[i4];
      a = fmaf(wv.x, g1[4*i4], a);   a = fmaf(wv.y, g1[4*i4+1], a);
      a = fmaf(wv.z, g1[4*i4+2], a); a = fmaf(wv.w, g1[4*i4+3], a);
    }
    const float v = a - 0.25f;   // boost=0, -LOAD_PEN*usage = -0.25
    bal[t] = v;
    outBal[b*8 + t] = v;
  }
  __syncthreads();
  if (t == 0) {
    int t0 = 0; float b0 = bal[0];
    #pragma unroll
    for (int e2 = 1; e2 < 8; ++e2) if (bal[e2] > b0) { b0 = bal[e2]; t0 = e2; }
    int t1 = -1; float b1 = -3.4e38f;
    #pragma unroll
    for (int e2 = 0; e2 < 8; ++e2) if (e2 != t0 && bal[e2] > b1) { b1 = bal[e2]; t1 = e2; }
    tk[b*2] = t0; tk[b*2 + 1] = t1;
  }
}

// =================== serial capacity-constrained routing ===================
__global__ __launch_bounds__(256) void route_kernel(const int* __restrict__ tk,
                                                    int* __restrict__ chosen,
                                                    float* __restrict__ outD)
{
  __shared__ int stk[512];
  __shared__ int sch[256];
  const int t = threadIdx.x;
  stk[t] = tk[t]; stk[256 + t] = tk[256 + t];
  __syncthreads();
  if (t == 0) {
    float L0=0,L1=0,L2=0,L3=0,L4=0,L5=0,L6=0,L7=0;
    for (int i = 0; i < 256; ++i) {
      const int a = stk[2*i], c = stk[2*i+1];
      const float la = (a==0)?L0:(a==1)?L1:(a==2)?L2:(a==3)?L3:(a==4)?L4:(a==5)?L5:(a==6)?L6:L7;
      const float lc = (c==0)?L0:(c==1)?L1:(c==2)?L2:(c==3)?L3:(c==4)?L4:(c==5)?L5:(c==6)?L6:L7;
      const int ch = (la < 48.f) ? a : ((lc < 48.f) ? c : ((la <= lc) ? a : c));
      L0 += (ch==0)?1.f:0.f; L1 += (ch==1)?1.f:0.f; L2 += (ch==2)?1.f:0.f; L3 += (ch==3)?1.f:0.f;
      L4 += (ch==4)?1.f:0.f; L5 += (ch==5)?1.f:0.f; L6 += (ch==6)?1.f:0.f; L7 += (ch==7)?1.f:0.f;
      sch[i] = ch;
    }
  }
  __syncthreads();
  const int ch = sch[t];
  chosen[t] = ch;
  #pragma unroll
  for (int e2 = 0; e2 < 8; ++e2) outD[t*8 + e2] = (ch == e2) ? 1.f : 0.f;
}

// ============ expert phase A: conv1 3->32 (32x32) + pool -> P1g ============
__global__ __launch_bounds__(128) void expA_kernel(
    const float* __restrict__ x, const int* __restrict__ chosen,
    const float* __restrict__ ew1, const float* __restrict__ eg1,
    const float* __restrict__ eb1, float* __restrict__ P1g)
{
  __shared__ __align__(16) float sxe[1020];  // x slab [3][10][34]
  __shared__ __align__(16) float sw1[864];
  __shared__ float bs[32], bb[32];
  const int t = threadIdx.x;
  const int b = blockIdx.x >> 2, q = blockIdx.x & 3;
  const int r0 = q * 8;
  const int e = chosen[b];

  for (int j = t; j < 1020; j += 128) {
    int ic = j / 340, r = (j % 340) / 34, c = j % 34;
    int gy = r0 - 1 + r, gx = c - 1;
    float v = 0.f;
    if (gy >= 0 && gy < 32 && gx >= 0 && gx < 32) v = x[b*3072 + ic*1024 + gy*32 + gx];
    sxe[j] = v;
  }
  for (int j = t; j < 864; j += 128) sw1[j] = ew1[e*864 + j];
  if (t < 32) { bs[t] = eg1[e*32 + t]*BN_RS; bb[t] = eb1[e*32 + t]; }
  __syncthreads();

  const int oc = t >> 2, pr = t & 3;
  float acc[2][32];
  #pragma unroll
  for (int dy = 0; dy < 2; ++dy)
    #pragma unroll
    for (int xx = 0; xx < 32; ++xx) acc[dy][xx] = 0.f;

  for (int ic = 0; ic < 3; ++ic) {
    float w[9];
    #pragma unroll
    for (int k = 0; k < 9; ++k) w[k] = sw1[oc*27 + ic*9 + k];
    #pragma unroll
    for (int wr = 0; wr < 4; ++wr) {
      float rv[34];
      const float2* rp = (const float2*)&sxe[ic*340 + (2*pr + wr)*34];
      #pragma unroll
      for (int j2 = 0; j2 < 17; ++j2) { float2 v2 = rp[j2]; rv[2*j2] = v2.x; rv[2*j2+1] = v2.y; }
      #pragma unroll
      for (int dy = 0; dy < 2; ++dy) {
        const int ky = wr - dy;
        if (ky < 0 || ky > 2) continue;
        #pragma unroll
        for (int xx = 0; xx < 32; ++xx)
          #pragma unroll
          for (int kx = 0; kx < 3; ++kx)
            acc[dy][xx] = fmaf(w[ky*3 + kx], rv[xx + kx], acc[dy][xx]);
      }
    }
  }
  const float s = bs[oc], bo = bb[oc];
  float o16[16];
  #pragma unroll
  for (int pc = 0; pc < 16; ++pc) {
    float v0 = fmaxf(fmaf(acc[0][2*pc],   s, bo), 0.f);
    float v1 = fmaxf(fmaf(acc[0][2*pc+1], s, bo), 0.f);
    float v2 = fmaxf(fmaf(acc[1][2*pc],   s, bo), 0.f);
    float v3 = fmaxf(fmaf(acc[1][2*pc+1], s, bo), 0.f);
    o16[pc] = fmaxf(fmaxf(v0, v1), fmaxf(v2, v3));
  }
  float4* dst = (float4*)&P1g[b*8192 + oc*256 + (q*4 + pr)*16];
  #pragma unroll
  for (int j4 = 0; j4 < 4; ++j4) {
    float4 v; v.x = o16[4*j4]; v.y = o16[4*j4+1]; v.z = o16[4*j4+2]; v.w = o16[4*j4+3];
    dst[j4] = v;
  }
}

// ========= expert phase B: conv2 32->64 (16x16) + pool -> P2g ==============
// grid 512 = sample*2 + rh(8-row half); 256 thr = ocg(16 x 4oc) x ih x cp(8)
#define B_SP1 0        // [32][10][18], data col d at d+1
#define B_WD  5760     // 2 x [2part][4icl][9][64oc] = 2x4608
#define B_BS  14976
#define B_BB  15040
__global__ __launch_bounds__(256) void expB_kernel(
    const int* __restrict__ chosen, const float* __restrict__ P1g,
    const float* __restrict__ ew2t, const float* __restrict__ eg2,
    const float* __restrict__ eb2, float* __restrict__ P2g)
{
  __shared__ __align__(16) float sm[15104];
  const int t = threadIdx.x;
  const int b = blockIdx.x >> 1, rh = blockIdx.x & 1;
  const int e = chosen[b];

  // stage sP1 (10 rows: abs 8rh-1 .. 8rh+8, zero out-of-range) + col pads
  const float4* P1g4 = (const float4*)P1g;
  for (int j = t; j < 1280; j += 256) {
    int ic = j / 40, rem = j % 40, rr = rem / 4, cq = rem % 4;
    int ar = rh*8 - 1 + rr;
    float4 v = make_float4(0.f, 0.f, 0.f, 0.f);
    if (ar >= 0 && ar < 16) v = P1g4[b*2048 + ic*64 + ar*4 + cq];
    int base = B_SP1 + ic*180 + rr*18 + 1 + 4*cq;
    sm[base] = v.x; sm[base+1] = v.y; sm[base+2] = v.z; sm[base+3] = v.w;
  }
  for (int j = t; j < 640; j += 256) {
    int ic = j / 20, rr = (j % 20) / 2, side = j & 1;
    sm[B_SP1 + ic*180 + rr*18 + side*17] = 0.f;
  }
  if (t < 64) { sm[B_BS + t] = eg2[e*64 + t]*BN_RS; sm[B_BB + t] = eb2[e*64 + t]; }
  // stage w chunk 0 (part0: ics 0..3, part1: ics 16..19)
  for (int jj = t; jj < 4608; jj += 256) {
    int part = jj / 2304, r = jj % 2304;
    sm[B_WD + jj] = ew2t[e*18432 + (16*part)*576 + r];
  }
  __syncthreads();

  const int ocg = t >> 4, ih = (t >> 3) & 1, cp = t & 7;
  float acc[4][8][2];
  #pragma unroll
  for (int o = 0; o < 4; ++o)
    #pragma unroll
    for (int r = 0; r < 8; ++r) { acc[o][r][0] = 0.f; acc[o][r][1] = 0.f; }

  for (int cc = 0; cc < 4; ++cc) {
    if (cc > 0) __syncthreads();
    if (cc < 3) {
      const int buf = (cc + 1) & 1;
      for (int jj = t; jj < 4608; jj += 256) {
        int part = jj / 2304, r = jj % 2304;
        sm[B_WD + buf*4608 + jj] = ew2t[e*18432 + (16*part + 4*(cc+1))*576 + r];
      }
    }
    const float* wb = &sm[B_WD + (cc & 1)*4608 + ih*2304];
    #pragma unroll
    for (int icl = 0; icl < 4; ++icl) {
      const int ic = 16*ih + 4*cc + icl;
      float w[4][9];
      #pragma unroll
      for (int k = 0; k < 9; ++k) {
        float4 wv = *(const float4*)&wb[icl*576 + k*64 + 4*ocg];
        w[0][k] = wv.x; w[1][k] = wv.y; w[2][k] = wv.z; w[3][k] = wv.w;
      }
      const float* src = &sm[B_SP1 + ic*180 + 2*cp];
      #pragma unroll
      for (int rr = 0; rr < 10; ++rr) {
        float2 va = *(const float2*)&src[rr*18];
        float2 vb = *(const float2*)&src[rr*18 + 2];
        const float iv0 = va.x, iv1 = va.y, iv2 = vb.x, iv3 = vb.y;
        #pragma unroll
        for (int o = 0; o < 8; ++o) {
          const int ky = rr - o;
          if (ky < 0 || ky > 2) continue;
          #pragma unroll
          for (int oo = 0; oo < 4; ++oo) {
            acc[oo][o][0] = fmaf(w[oo][ky*3+0], iv0, acc[oo][o][0]);
            acc[oo][o][1] = fmaf(w[oo][ky*3+0], iv1, acc[oo][o][1]);
            acc[oo][o][0] = fmaf(w[oo][ky*3+1], iv1, acc[oo][o][0]);
            acc[oo][o][1] = fmaf(w[oo][ky*3+1], iv2, acc[oo][o][1]);
            acc[oo][o][0] = fmaf(w[oo][ky*3+2], iv2, acc[oo][o][0]);
            acc[oo][o][1] = fmaf(w[oo][ky*3+2], iv3, acc[oo][o][1]);
          }
        }
      }
    }
  }

  // ic-split exchange
  __syncthreads();
  const int slot = ocg*8 + cp;
  if (ih == 1) {
    #pragma unroll
    for (int o = 0; o < 4; ++o)
      #pragma unroll
      for (int r = 0; r < 8; ++r) {
        sm[slot*65 + o*16 + r*2 + 0] = acc[o][r][0];
        sm[slot*65 + o*16 + r*2 + 1] = acc[o][r][1];
      }
  }
  __syncthreads();
  if (ih == 0) {
    #pragma unroll
    for (int o = 0; o < 4; ++o) {
      const int oc = 4*ocg + o;
      const float s = sm[B_BS + oc], bo = sm[B_BB + oc];
      #pragma unroll
      for (int pr = 0; pr < 4; ++pr) {
        float c00 = acc[o][2*pr][0]   + sm[slot*65 + o*16 + (2*pr)*2 + 0];
        float c01 = acc[o][2*pr][1]   + sm[slot*65 + o*16 + (2*pr)*2 + 1];
        float c10 = acc[o][2*pr+1][0] + sm[slot*65 + o*16 + (2*pr+1)*2 + 0];
        float c11 = acc[o][2*pr+1][1] + sm[slot*65 + o*16 + (2*pr+1)*2 + 1];
        float v0 = fmaxf(fmaf(c00, s, bo), 0.f);
        float v1 = fmaxf(fmaf(c01, s, bo), 0.f);
        float v2 = fmaxf(fmaf(c10, s, bo), 0.f);
        float v3 = fmaxf(fmaf(c11, s, bo), 0.f);
        P2g[b*4096 + oc*64 + (rh*4 + pr)*8 + cp] =
            fmaxf(fmaxf(v0, v1), fmaxf(v2, v3));
      }
    }
  }
}

// ====== expert phase C: conv3 64->128 (8x8) + bn/relu + GAP -> featg =======
// grid 512 = sample*2 + oc-half(64); 256 thr = ocg(16 x 4oc) x ihq(4) x cp(4)
#define C_SP2 0        // [64][10][12], data col d at d+1
#define C_WD  7680     // 2 bufs x [4part][9][64oc] part-stride 592 => 2x2368
#define C_BS  12416
#define C_BB  12480
#define C_EXA 0
#define C_EXB 4176
__global__ __launch_bounds__(256) void expC_kernel(
    const int* __restrict__ chosen, const float* __restrict__ P2g,
    const float* __restrict__ ew3t, const float* __restrict__ eg3,
    const float* __restrict__ eb3, float* __restrict__ featg)
{
  __shared__ __align__(16) float sm[12544];
  const int t = threadIdx.x;
  const int b = blockIdx.x >> 1, half = blockIdx.x & 1, oc0 = half*64;
  const int e = chosen[b];

  // stage sP2 interior + borders
  const float4* P2g4 = (const float4*)P2g;
  for (int j = t; j < 1024; j += 256) {
    int oc = j >> 4, rem = j & 15, row = rem >> 1, cq = rem & 1;
    float4 v = P2g4[b*1024 + j];
    int base = C_SP2 + oc*120 + (row + 1)*12 + 1 + 4*cq;
    sm[base] = v.x; sm[base+1] = v.y; sm[base+2] = v.z; sm[base+3] = v.w;
  }
  for (int j = t; j < 2560; j += 256) {
    int ic = j / 40, rem = j % 40, r, c;
    if (rem < 12)      { r = 0; c = rem; }
    else if (rem < 24) { r = 9; c = rem - 12; }
    else if (rem < 32) { r = rem - 24 + 1; c = 0; }
    else               { r = rem - 32 + 1; c = 9; }
    sm[C_SP2 + ic*120 + r*12 + c] = 0.f;
  }
  if (t < 64) { sm[C_BS + t] = eg3[e*128 + oc0 + t]*BN_RS; sm[C_BB + t] = eb3[e*128 + oc0 + t]; }
  // stage w chunk 0: parts p stage ic = 16p + 0
  for (int jj = t; jj < 2304; jj += 256) {
    int p = jj / 576, r = jj % 576, k = r / 64, ocl = r % 64;
    sm[C_WD + p*592 + r] = ew3t[e*73728 + (16*p)*1152 + k*128 + oc0 + ocl];
  }
  __syncthreads();

  const int ocg = t >> 4, ihq = (t >> 2) & 3, cp = t & 3;
  float acc[4][8][2];
  #pragma unroll
  for (int o = 0; o < 4; ++o)
    #pragma unroll
    for (int r = 0; r < 8; ++r) { acc[o][r][0] = 0.f; acc[o][r][1] = 0.f; }

  for (int cc = 0; cc < 16; ++cc) {
    if (cc > 0) __syncthreads();
    if (cc < 15) {
      const int buf = (cc + 1) & 1;
      for (int jj = t; jj < 2304; jj += 256) {
        int p = jj / 576, r = jj % 576, k = r / 64, ocl = r % 64;
        sm[C_WD + buf*2368 + p*592 + r] =
            ew3t[e*73728 + (16*p + cc + 1)*1152 + k*128 + oc0 + ocl];
      }
    }
    const int ic = 16*ihq + cc;
    const float* wb = &sm[C_WD + (cc & 1)*2368 + ihq*592];
    float w[4][9];
    #pragma unroll
    for (int k = 0; k < 9; ++k) {
      float4 wv = *(const float4*)&wb[k*64 + 4*ocg];
      w[0][k] = wv.x; w[1][k] = wv.y; w[2][k] = wv.z; w[3][k] = wv.w;
    }
    const float* src = &sm[C_SP2 + ic*120 + 2*cp];
    #pragma unroll
    for (int rr = 0; rr < 10; ++rr) {
      float2 va = *(const float2*)&src[rr*12];
      float2 vb = *(const float2*)&src[rr*12 + 2];
      const float iv0 = va.x, iv1 = va.y, iv2 = vb.x, iv3 = vb.y;
      #pragma unroll
      for (int o = 0; o < 8; ++o) {
        const int ky = rr - o;
        if (ky < 0 || ky > 2) continue;
        #pragma unroll
        for (int oo = 0; oo < 4; ++oo) {
          acc[oo][o][0] = fmaf(w[oo][ky*3+0], iv0, acc[oo][o][0]);
          acc[oo][o][1] = fmaf(w[oo][ky*3+0], iv1, acc[oo][o][1]);
          acc[oo][o][0] = fmaf(w[oo][ky*3+1], iv1, acc[oo][o][0]);
          acc[oo][o][1] = fmaf(w[oo][ky*3+1], iv2, acc[oo][o][1]);
          acc[oo][o][0] = fmaf(w[oo][ky*3+2], iv2, acc[oo][o][0]);
          acc[oo][o][1] = fmaf(w[oo][ky*3+2], iv3, acc[oo][o][1]);
        }
      }
    }
  }

  // 4-way ic-split tree exchange (overlay sP2/w regions; both dead)
  __syncthreads();
  const int slot = ocg*4 + cp;
  if (ihq == 1 || ihq == 3) {
    const int base = (ihq == 1 ? C_EXA : C_EXB) + slot*65;
    #pragma unroll
    for (int o = 0; o < 4; ++o)
      #pragma unroll
      for (int r = 0; r < 8; ++r) {
        sm[base + o*16 + r*2 + 0] = acc[o][r][0];
        sm[base + o*16 + r*2 + 1] = acc[o][r][1];
      }
  }
  __syncthreads();
  if (ihq == 0 || ihq == 2) {
    const int base = (ihq == 0 ? C_EXA : C_EXB) + slot*65;
    #pragma unroll
    for (int o = 0; o < 4; ++o)
      #pragma unroll
      for (int r = 0; r < 8; ++r) {
        acc[o][r][0] += sm[base + o*16 + r*2 + 0];
        acc[o][r][1] += sm[base + o*16 + r*2 + 1];
      }
  }
  __syncthreads();
  if (ihq == 2) {
    const int base = C_EXA + slot*65;
    #pragma unroll
    for (int o = 0; o < 4; ++o)
      #pragma unroll
      for (int r = 0; r < 8; ++r) {
        sm[base + o*16 + r*2 + 0] = acc[o][r][0];
        sm[base + o*16 + r*2 + 1] = acc[o][r][1];
      }
  }
  __syncthreads();
  if (ihq == 0) {
    const int base = C_EXA + slot*65;
    #pragma unroll
    for (int o = 0; o < 4; ++o) {
      const int oc = 4*ocg + o;
      const float s = sm[C_BS + oc], bo = sm[C_BB + oc];
      float g = 0.f;
      #pragma unroll
      for (int r = 0; r < 8; ++r) {
        float c0 = acc[o][r][0] + sm[base + o*16 + r*2 + 0];
        float c1 = acc[o][r][1] + sm[base + o*16 + r*2 + 1];
        g += fmaxf(fmaf(c0, s, bo), 0.f);
        g += fmaxf(fmaf(c1, s, bo), 0.f);
      }
      g += __shfl_xor(g, 1);
      g += __shfl_xor(g, 2);
      if ((t & 3) == 0) featg[b*128 + oc0 + oc] = g * (1.f/64.f);
    }
  }
}

// ================= expert phase D: FC chain -> final =======================
__global__ __launch_bounds__(128) void expD_kernel(
    const int* __restrict__ chosen, const float* __restrict__ featg,
    const float* __restrict__ efw, const float* __restrict__ efb,
    const float* __restrict__ cw1, const float* __restrict__ cb1,
    const float* __restrict__ cw2, const float* __restrict__ cb2,
    float* __restrict__ outF)
{
  __shared__ float sf[128], sff[128], sgg[64];
  const int b = blockIdx.x, t = threadIdx.x;
  const int e = chosen[b];
  sf[t] = featg[b*128 + t];
  __syncthreads();
  {
    float a = efb[e*128 + t];
    const float4* wp = (const float4*)&efw[e*16384 + t*128];
    #pragma unroll 8
    for (int i4 = 0; i4 < 32; ++i4) {
      float4 wv = wp[i4];
      a = fmaf(wv.x, sf[4*i4], a);   a = fmaf(wv.y, sf[4*i4+1], a);
      a = fmaf(wv.z, sf[4*i4+2], a); a = fmaf(wv.w, sf[4*i4+3], a);
    }
    sff[t] = fmaxf(a, 0.f);
  }
  __syncthreads();
  if (t < 64) {
    float a = cb1[e*64 + t];
    const float4* wp = (const float4*)&cw1[e*8192 + t*128];
    #pragma unroll 8
    for (int i4 = 0; i4 < 32; ++i4) {
      float4 wv = wp[i4];
      a = fmaf(wv.x, sff[4*i4], a);   a = fmaf(wv.y, sff[4*i4+1], a);
      a = fmaf(wv.z, sff[4*i4+2], a); a = fmaf(wv.w, sff[4*i4+3], a);
    }
    sgg[t] = fmaxf(a, 0.f);
  }
  __syncthreads();
  if (t < 10) {
    float a = cb2[e*10 + t];
    const float4* wp = (const float4*)&cw2[e*640 + t*64];
    #pragma unroll
    for (int i4 = 0; i4 < 16; ++i4) {
      float4 wv = wp[i4];
      a = fmaf(wv.x, sgg[4*i4], a);   a = fmaf(wv.y, sgg[4*i4+1], a);
      a = fmaf(wv.z, sgg[4*i4+2], a); a = fmaf(wv.w, sgg[4*i4+3], a);
    }
    outF[b*10 + t] = a;   // routing weight is exactly 1.0 for the chosen expert
  }
}

// ================================ host =====================================
extern "C" void kernel_launch(void* const* d_in, const int* in_sizes, int n_in,
                              void* d_out, int out_size, void* d_ws, size_t ws_size,
                              hipStream_t stream)
{
  const float* x   = (const float*)d_in[0];
  const float* tw1 = (const float*)d_in[1];
  const float* tg1 = (const float*)d_in[2];
  const float* tb1 = (const float*)d_in[3];
  const float* tw2 = (const float*)d_in[4];
  const float* tg2 = (const float*)d_in[5];
  const float* tb2 = (const float*)d_in[6];
  const float* tfw = (const float*)d_in[7];
  const float* tfb = (const float*)d_in[8];
  const float* gw1 = (const float*)d_in[9];
  const float* gb1 = (const float*)d_in[10];
  const float* gw2 = (const float*)d_in[11];
  const float* gb2 = (const float*)d_in[12];
  const float* ew1 = (const float*)d_in[13];
  const float* eg1 = (const float*)d_in[14];
  const float* eb1 = (const float*)d_in[15];
  const float* ew2 = (const float*)d_in[16];
  const float* eg2 = (const float*)d_in[17];
  const float* eb2 = (const float*)d_in[18];
  const float* ew3 = (const float*)d_in[19];
  const float* eg3 = (const float*)d_in[20];
  const float* eb3 = (const float*)d_in[21];
  const float* efw = (const float*)d_in[22];
  const float* efb = (const float*)d_in[23];
  const float* cw1 = (const float*)d_in[24];
  const float* cb1 = (const float*)d_in[25];
  const float* cw2 = (const float*)d_in[26];
  const float* cb2 = (const float*)d_in[27];

  float* out    = (float*)d_out;
  char*  ws     = (char*)d_ws;
  float* tfp    = (float*)(ws + WS_TFP);
  int*   tk     = (int*)(ws + WS_TK);
  int*   chosen = (int*)(ws + WS_CHOSEN);
  float* featg  = (float*)(ws + WS_FEATG);
  float* P1g    = (float*)(ws + WS_P1G);
  float* P2g    = (float*)(ws + WS_P2G);
  float* tw2t   = (float*)(ws + WS_TW2T);
  float* ew2t   = (float*)(ws + WS_EW2T);
  float* ew3t   = (float*)(ws + WS_EW3T);

  prep_kernel<<<2916, 256, 0, stream>>>(tw2, ew2, ew3, tw2t, ew2t, ew3t);
  trunk_kernel<<<1024, 256, 0, stream>>>(x, tw1, tg1, tb1, tw2t, tg2, tb2, tfp);
  gate_kernel<<<256, 64, 0, stream>>>(tfp, tfw, tfb, gw1, gb1, gw2, gb2, out + 2560, tk);
  route_kernel<<<1, 256, 0, stream>>>(tk, chosen, out + 4608);
  expA_kernel<<<1024, 128, 0, stream>>>(x, chosen, ew1, eg1, eb1, P1g);
  expB_kernel<<<512, 256, 0, stream>>>(chosen, P1g, ew2t, eg2, eb2, P2g);
  expC_kernel<<<512, 256, 0, stream>>>(chosen, P2g, ew3t, eg3, eb3, featg);
  expD_kernel<<<256, 128, 0, stream>>>(chosen, featg, efw, efb, cw1, cb1, cw2, cb2, out);
}

// Round 4
// 432.690 us; speedup vs baseline: 1.0575x; 1.0575x over previous
//
#include <hip/hip_runtime.h>
#include <hip/hip_bf16.h>
#include <math.h>

// ---------------------------------------------------------------------------
// DistributedMoE forward, MI355X — R4: conflict-free lane=column convs AT
// LOW VGPR (acc[4][8], ~100 VGPR, 4 waves/SIMD) and LDS <= 53KB (3 blk/CU).
// R3 lesson: occupancy >= conflicts; R3's conflict fix cost VGPR 176 / 62KB
// LDS and regressed. This round keeps both under the cliffs.
// One expert per sample (softmax over one dispatched element == 1).
//
// out (fp32): final[256,10] @0, balanced[256,8] @2560, D[256,8] @4608
// ---------------------------------------------------------------------------

#define BN_RS (1.0f / sqrtf(1.00001f))

// ws byte offsets
#define WS_TF     0          // f32[256*128]
#define WS_TK     131072     // i32[512]
#define WS_CHOSEN 133120     // i32[256]
#define WS_FEATG  134144     // f32[256*128]
#define WS_P1G    265216     // f32[256][32][16][16]
#define WS_P2G    8653824    // f32[256][64][8][8]
#define WS_TW2T   12848128   // f32[32ic][9][32oc]
#define WS_EW2T   12884992   // f32[8][32ic][9][64oc]
#define WS_EW3T   13474816   // f32[8][64ic][9][128oc]

// =================== prep: weight transposes to [ic][k][oc] ================
__global__ __launch_bounds__(256) void prep_kernel(
    const float* __restrict__ tw2, const float* __restrict__ ew2,
    const float* __restrict__ ew3, float* __restrict__ tw2t,
    float* __restrict__ ew2t, float* __restrict__ ew3t)
{
  const int j = blockIdx.x * 256 + threadIdx.x;
  if (j < 9216) {
    int ic = j / 288, rem = j % 288, k = rem / 32, oc = rem % 32;
    tw2t[j] = tw2[oc*288 + ic*9 + k];
  } else if (j < 156672) {
    int jj = j - 9216;
    int e = jj / 18432, r2 = jj % 18432, ic = r2 / 576, r3 = r2 % 576;
    int k = r3 / 64, oc = r3 % 64;
    ew2t[jj] = ew2[e*18432 + oc*288 + ic*9 + k];
  } else if (j < 746496) {
    int jj = j - 156672;
    int e = jj / 73728, r2 = jj % 73728, ic = r2 / 1152, r3 = r2 % 1152;
    int k = r3 / 128, oc = r3 % 128;
    ew3t[jj] = ew3[e*73728 + oc*576 + ic*9 + k];
  }
}

// ======================= trunk: conv1+conv2+pool+avg =======================
// grid 1024 = sample*4 + quadrant; 256 thr; LDS 51.2KB -> 3 blocks/CU.
// conv2 thread = g(8; 4oc) x lane32 (c = l&15 col, rh = l>>4 row-half).
#define T_SA1 0        // conv1 out [32][18][18] halo = 10368
#define T_SX  10368    // x tile [3][20][20] = 1200 (phase 1)
#define T_SW1 11568    // 864 (phase 1)
#define T_WD  10368    // phase 2: w2 dbuf 2 x [4ic][9][32oc] = 2304
#define T_S1  12672
#define T_O1  12704
#define T_S2  12736
#define T_O2  12768
__global__ __launch_bounds__(256) void trunk_kernel(
    const float* __restrict__ x, const float* __restrict__ tw1,
    const float* __restrict__ tg1, const float* __restrict__ tb1,
    const float* __restrict__ tw2t, const float* __restrict__ tg2,
    const float* __restrict__ tb2, float* __restrict__ tf)
{
  __shared__ __align__(16) float sm[12800];
  const int t = threadIdx.x;
  const int b = blockIdx.x >> 2, q = blockIdx.x & 3;
  const int qy = q >> 1, qx = q & 1;
  const int y0 = qy * 16, x0 = qx * 16;

  for (int j = t; j < 1200; j += 256) {
    int ic = j / 400, r = (j % 400) / 20, cxx = j % 20;
    int gy = y0 - 2 + r, gx = x0 - 2 + cxx;
    float v = 0.f;
    if (gy >= 0 && gy < 32 && gx >= 0 && gx < 32) v = x[b*3072 + ic*1024 + gy*32 + gx];
    sm[T_SX + j] = v;
  }
  for (int j = t; j < 864; j += 256) sm[T_SW1 + j] = tw1[j];
  if (t < 32) {
    sm[T_S1 + t] = tg1[t]*BN_RS; sm[T_O1 + t] = tb1[t];
    sm[T_S2 + t] = tg2[t]*BN_RS; sm[T_O2 + t] = tb2[t];
  }
  __syncthreads();

  // ---- conv1 -> sa1 [32][18][18] (proven R2 structure) ----
  for (int it = 0; it < 3; ++it) {
    const int item = it*256 + t;
    if (item < 576) {
      const int oc = item / 18, r = item % 18;
      const int gy = y0 - 1 + r;
      float acc1[18];
      #pragma unroll
      for (int c2 = 0; c2 < 18; ++c2) acc1[c2] = 0.f;
      if (gy >= 0 && gy < 32) {
        for (int ic = 0; ic < 3; ++ic) {
          float w[9];
          #pragma unroll
          for (int k = 0; k < 9; ++k) w[k] = sm[T_SW1 + oc*27 + ic*9 + k];
          #pragma unroll
          for (int wr = 0; wr < 3; ++wr) {
            float rv[20];
            const float4* rp = (const float4*)&sm[T_SX + ic*400 + (r + wr)*20];
            #pragma unroll
            for (int j4 = 0; j4 < 5; ++j4) {
              float4 v4 = rp[j4];
              rv[4*j4] = v4.x; rv[4*j4+1] = v4.y; rv[4*j4+2] = v4.z; rv[4*j4+3] = v4.w;
            }
            #pragma unroll
            for (int c2 = 0; c2 < 18; ++c2)
              #pragma unroll
              for (int kx = 0; kx < 3; ++kx)
                acc1[c2] = fmaf(w[wr*3 + kx], rv[c2 + kx], acc1[c2]);
          }
        }
      }
      const float s = sm[T_S1 + oc], bo = sm[T_O1 + oc];
      #pragma unroll
      for (int c2 = 0; c2 < 18; ++c2) {
        const int gx = x0 - 1 + c2;
        float v = 0.f;
        if (gy >= 0 && gy < 32 && gx >= 0 && gx < 32) v = fmaxf(fmaf(acc1[c2], s, bo), 0.f);
        sm[T_SA1 + oc*324 + r*18 + c2] = v;
      }
    }
  }
  __syncthreads();   // x tile / conv1 weights dead -> w2 dbuf region

  for (int j = t; j < 1152; j += 256) sm[T_WD + j] = tw2t[j];   // chunk 0
  __syncthreads();

  // ---- conv2 32->32 + pool + quadrant mean ----
  const int g = t >> 5, l = t & 31, c = l & 15, rh = l >> 4;
  float acc[4][8];
  #pragma unroll
  for (int o = 0; o < 4; ++o)
    #pragma unroll
    for (int r = 0; r < 8; ++r) acc[o][r] = 0.f;

  for (int cc = 0; cc < 8; ++cc) {
    if (cc < 7) {
      for (int j = t; j < 1152; j += 256)
        sm[T_WD + ((cc+1)&1)*1152 + j] = tw2t[(cc+1)*1152 + j];
    }
    const float* wb = &sm[T_WD + (cc & 1)*1152];
    #pragma unroll
    for (int icl = 0; icl < 4; ++icl) {
      const int ic = 4*cc + icl;
      float w[4][9];
      #pragma unroll
      for (int k = 0; k < 9; ++k) {
        float4 wv = *(const float4*)&wb[icl*288 + k*32 + 4*g];
        w[0][k] = wv.x; w[1][k] = wv.y; w[2][k] = wv.z; w[3][k] = wv.w;
      }
      const float* src = &sm[T_SA1 + ic*324 + rh*144 + c];
      #pragma unroll
      for (int rr = 0; rr < 10; ++rr) {
        const float i0 = src[rr*18], i1 = src[rr*18 + 1], i2 = src[rr*18 + 2];
        #pragma unroll
        for (int dr = 0; dr < 3; ++dr) {
          const int r = rr - dr;
          if (r < 0 || r > 7) continue;
          #pragma unroll
          for (int o = 0; o < 4; ++o) {
            acc[o][r] = fmaf(w[o][dr*3+0], i0, acc[o][r]);
            acc[o][r] = fmaf(w[o][dr*3+1], i1, acc[o][r]);
            acc[o][r] = fmaf(w[o][dr*3+2], i2, acc[o][r]);
          }
        }
      }
    }
    __syncthreads();
  }

  #pragma unroll
  for (int o = 0; o < 4; ++o) {
    const int oc = 4*g + o;
    const float s = sm[T_S2 + oc], bo = sm[T_O2 + oc];
    float m[4];
    #pragma unroll
    for (int pr = 0; pr < 4; ++pr) {
      float v0 = fmaxf(fmaf(acc[o][2*pr],   s, bo), 0.f);
      float v1 = fmaxf(fmaf(acc[o][2*pr+1], s, bo), 0.f);
      m[pr] = fmaxf(v0, v1);
    }
    float s4 = 0.f;
    #pragma unroll
    for (int pr = 0; pr < 4; ++pr) {
      float nb = __shfl_xor(m[pr], 1);
      s4 += fmaxf(m[pr], nb);
    }
    if (c & 1) s4 = 0.f;
    s4 += __shfl_xor(s4, 1);
    s4 += __shfl_xor(s4, 2);
    s4 += __shfl_xor(s4, 4);
    s4 += __shfl_xor(s4, 8);
    s4 += __shfl_xor(s4, 16);
    if (l == 0) tf[b*128 + oc*4 + qy*2 + qx] = s4 * (1.f/64.f);
  }
}

// ============================== gate + top2 ================================
__global__ __launch_bounds__(64) void gate_kernel(
    const float* __restrict__ tf, const float* __restrict__ tfw, const float* __restrict__ tfb,
    const float* __restrict__ gw1, const float* __restrict__ gb1,
    const float* __restrict__ gw2, const float* __restrict__ gb2,
    float* __restrict__ outBal, int* __restrict__ tk)
{
  __shared__ float feat[128], rf[64], g1[32], bal[8];
  const int b = blockIdx.x, t = threadIdx.x;
  feat[t] = tf[b*128 + t];
  feat[64 + t] = tf[b*128 + 64 + t];
  __syncthreads();
  {
    float a = tfb[t];
    const float4* wp = (const float4*)&tfw[t*128];
    #pragma unroll 8
    for (int i4 = 0; i4 < 32; ++i4) {
      float4 wv = wp[i4];
      a = fmaf(wv.x, feat[4*i4], a);   a = fmaf(wv.y, feat[4*i4+1], a);
      a = fmaf(wv.z, feat[4*i4+2], a); a = fmaf(wv.w, feat[4*i4+3], a);
    }
    rf[t] = fmaxf(a, 0.f);
  }
  __syncthreads();
  if (t < 32) {
    float a = gb1[t];
    const float4* wp = (const float4*)&gw1[t*64];
    #pragma unroll
    for (int i4 = 0; i4 < 16; ++i4) {
      float4 wv = wp[i4];
      a = fmaf(wv.x, rf[4*i4], a);   a = fmaf(wv.y, rf[4*i4+1], a);
      a = fmaf(wv.z, rf[4*i4+2], a); a = fmaf(wv.w, rf[4*i4+3], a);
    }
    g1[t] = fmaxf(a, 0.f);
  }
  __syncthreads();
  if (t < 8) {
    float a = gb2[t];
    const float4* wp = (const float4*)&gw2[t*32];
    #pragma unroll
    for (int i4 = 0; i4 < 8; ++i4) {
      float4 wv = wp[i4];
      a = fmaf(wv.x, g1[4*i4], a);   a = fmaf(wv.y, g1[4*i4+1], a);
      a = fmaf(wv.z, g1[4*i4+2], a); a = fmaf(wv.w, g1[4*i4+3], a);
    }
    const float v = a - 0.25f;   // boost=0, -LOAD_PEN*usage = -0.25
    bal[t] = v;
    outBal[b*8 + t] = v;
  }
  __syncthreads();
  if (t == 0) {
    int t0 = 0; float b0 = bal[0];
    #pragma unroll
    for (int e2 = 1; e2 < 8; ++e2) if (bal[e2] > b0) { b0 = bal[e2]; t0 = e2; }
    int t1 = -1; float b1 = -3.4e38f;
    #pragma unroll
    for (int e2 = 0; e2 < 8; ++e2) if (e2 != t0 && bal[e2] > b1) { b1 = bal[e2]; t1 = e2; }
    tk[b*2] = t0; tk[b*2 + 1] = t1;
  }
}

// =================== serial capacity-constrained routing ===================
__global__ __launch_bounds__(256) void route_kernel(const int* __restrict__ tk,
                                                    int* __restrict__ chosen,
                                                    float* __restrict__ outD)
{
  __shared__ int stk[512];
  __shared__ int sch[256];
  const int t = threadIdx.x;
  stk[t] = tk[t]; stk[256 + t] = tk[256 + t];
  __syncthreads();
  if (t == 0) {
    float L0=0,L1=0,L2=0,L3=0,L4=0,L5=0,L6=0,L7=0;
    for (int i = 0; i < 256; ++i) {
      const int a = stk[2*i], c = stk[2*i+1];
      const float la = (a==0)?L0:(a==1)?L1:(a==2)?L2:(a==3)?L3:(a==4)?L4:(a==5)?L5:(a==6)?L6:L7;
      const float lc = (c==0)?L0:(c==1)?L1:(c==2)?L2:(c==3)?L3:(c==4)?L4:(c==5)?L5:(c==6)?L6:L7;
      const int ch = (la < 48.f) ? a : ((lc < 48.f) ? c : ((la <= lc) ? a : c));
      L0 += (ch==0)?1.f:0.f; L1 += (ch==1)?1.f:0.f; L2 += (ch==2)?1.f:0.f; L3 += (ch==3)?1.f:0.f;
      L4 += (ch==4)?1.f:0.f; L5 += (ch==5)?1.f:0.f; L6 += (ch==6)?1.f:0.f; L7 += (ch==7)?1.f:0.f;
      sch[i] = ch;
    }
  }
  __syncthreads();
  const int ch = sch[t];
  chosen[t] = ch;
  #pragma unroll
  for (int e2 = 0; e2 < 8; ++e2) outD[t*8 + e2] = (ch == e2) ? 1.f : 0.f;
}

// ============ expert phase A: conv1 3->32 (32x32) + pool -> P1g ============
// grid 1024 = sample*4 + slab(8 rows); 256 thr = g(8; 4oc) x c(32 cols)
__global__ __launch_bounds__(256) void expA_kernel(
    const float* __restrict__ x, const int* __restrict__ chosen,
    const float* __restrict__ ew1, const float* __restrict__ eg1,
    const float* __restrict__ eb1, float* __restrict__ P1g)
{
  __shared__ __align__(16) float sxa[1020];   // [3][10][34]
  __shared__ __align__(16) float sw1t[864];   // [3ic][9][32oc]
  __shared__ float bs[32], bb[32];
  const int t = threadIdx.x;
  const int b = blockIdx.x >> 2, q = blockIdx.x & 3;
  const int r0 = q * 8;
  const int e = chosen[b];

  for (int j = t; j < 1020; j += 256) {
    int ic = j / 340, r = (j % 340) / 34, cxx = j % 34;
    int gy = r0 - 1 + r, gx = cxx - 1;
    float v = 0.f;
    if (gy >= 0 && gy < 32 && gx >= 0 && gx < 32) v = x[b*3072 + ic*1024 + gy*32 + gx];
    sxa[j] = v;
  }
  for (int j = t; j < 864; j += 256) {
    int oc = j / 27, r = j % 27, ic = r / 9, k = r % 9;
    sw1t[ic*288 + k*32 + oc] = ew1[e*864 + j];
  }
  if (t < 32) { bs[t] = eg1[e*32 + t]*BN_RS; bb[t] = eb1[e*32 + t]; }
  __syncthreads();

  const int g = t >> 5, c = t & 31;
  float acc[4][8];
  #pragma unroll
  for (int o = 0; o < 4; ++o)
    #pragma unroll
    for (int r = 0; r < 8; ++r) acc[o][r] = 0.f;

  for (int ic = 0; ic < 3; ++ic) {
    float w[4][9];
    #pragma unroll
    for (int k = 0; k < 9; ++k) {
      float4 wv = *(const float4*)&sw1t[ic*288 + k*32 + 4*g];
      w[0][k] = wv.x; w[1][k] = wv.y; w[2][k] = wv.z; w[3][k] = wv.w;
    }
    const float* src = &sxa[ic*340 + c];
    #pragma unroll
    for (int rr = 0; rr < 10; ++rr) {
      const float i0 = src[rr*34], i1 = src[rr*34 + 1], i2 = src[rr*34 + 2];
      #pragma unroll
      for (int dr = 0; dr < 3; ++dr) {
        const int r = rr - dr;
        if (r < 0 || r > 7) continue;
        #pragma unroll
        for (int o = 0; o < 4; ++o) {
          acc[o][r] = fmaf(w[o][dr*3+0], i0, acc[o][r]);
          acc[o][r] = fmaf(w[o][dr*3+1], i1, acc[o][r]);
          acc[o][r] = fmaf(w[o][dr*3+2], i2, acc[o][r]);
        }
      }
    }
  }

  #pragma unroll
  for (int o = 0; o < 4; ++o) {
    const int oc = 4*g + o;
    const float s = bs[oc], bo = bb[oc];
    float m[4];
    #pragma unroll
    for (int pr = 0; pr < 4; ++pr) {
      float v0 = fmaxf(fmaf(acc[o][2*pr],   s, bo), 0.f);
      float v1 = fmaxf(fmaf(acc[o][2*pr+1], s, bo), 0.f);
      m[pr] = fmaxf(v0, v1);
    }
    #pragma unroll
    for (int pr = 0; pr < 4; ++pr) {
      float nb = __shfl_xor(m[pr], 1);
      m[pr] = fmaxf(m[pr], nb);
    }
    if (!(c & 1)) {
      const int pc = c >> 1;
      #pragma unroll
      for (int pr = 0; pr < 4; ++pr)
        P1g[b*8192 + oc*256 + (q*4 + pr)*16 + pc] = m[pr];
    }
  }
}

// ========= expert phase B: conv2 32->64 (16x16) + pool -> P2g ==============
// grid 512 = sample*2 + oc-half; 256 thr = g(8; 4oc) x (c=l&15, rh=l>>4)
#define B_SP1 0       // [32][18][18] = 10368
#define B_WD  10368   // dbuf 2 x [4ic][9][32oc] = 2304
#define B_BS  12672
#define B_BB  12704
__global__ __launch_bounds__(256) void expB_kernel(
    const int* __restrict__ chosen, const float* __restrict__ P1g,
    const float* __restrict__ ew2t, const float* __restrict__ eg2,
    const float* __restrict__ eb2, float* __restrict__ P2g)
{
  __shared__ __align__(16) float sm[12736];
  const int t = threadIdx.x;
  const int b = blockIdx.x >> 1, och = blockIdx.x & 1, oc0 = 32*och;
  const int e = chosen[b];

  for (int j = t; j < 2176; j += 256) {
    int ic = j / 68, rr = j % 68, r, cxx;
    if (rr < 18)      { r = 0;  cxx = rr; }
    else if (rr < 36) { r = 17; cxx = rr - 18; }
    else { int rr2 = rr - 36; r = 1 + (rr2 >> 1); cxx = (rr2 & 1) * 17; }
    sm[B_SP1 + ic*324 + r*18 + cxx] = 0.f;
  }
  const float4* P1g4 = (const float4*)P1g;
  for (int j = t; j < 2048; j += 256) {
    int ic = j >> 6, rem = j & 63, row = rem >> 2, cq = rem & 3;
    float4 v = P1g4[b*2048 + j];
    int base = B_SP1 + ic*324 + (row + 1)*18 + 1 + 4*cq;
    sm[base] = v.x; sm[base+1] = v.y; sm[base+2] = v.z; sm[base+3] = v.w;
  }
  if (t < 32) { sm[B_BS + t] = eg2[e*64 + oc0 + t]*BN_RS; sm[B_BB + t] = eb2[e*64 + oc0 + t]; }
  for (int j = t; j < 1152; j += 256) {           // chunk 0 (ic 0..3)
    int icl = j / 288, r = j % 288, k = r / 32, ocl = r & 31;
    sm[B_WD + j] = ew2t[e*18432 + icl*576 + k*64 + oc0 + ocl];
  }
  __syncthreads();

  const int g = t >> 5, l = t & 31, c = l & 15, rh = l >> 4;
  float acc[4][8];
  #pragma unroll
  for (int o = 0; o < 4; ++o)
    #pragma unroll
    for (int r = 0; r < 8; ++r) acc[o][r] = 0.f;

  for (int cc = 0; cc < 8; ++cc) {
    if (cc < 7) {
      for (int j = t; j < 1152; j += 256) {
        int icl = j / 288, r = j % 288, k = r / 32, ocl = r & 31;
        sm[B_WD + ((cc+1)&1)*1152 + j] =
            ew2t[e*18432 + (4*(cc+1) + icl)*576 + k*64 + oc0 + ocl];
      }
    }
    const float* wb = &sm[B_WD + (cc & 1)*1152];
    #pragma unroll
    for (int icl = 0; icl < 4; ++icl) {
      const int ic = 4*cc + icl;
      float w[4][9];
      #pragma unroll
      for (int k = 0; k < 9; ++k) {
        float4 wv = *(const float4*)&wb[icl*288 + k*32 + 4*g];
        w[0][k] = wv.x; w[1][k] = wv.y; w[2][k] = wv.z; w[3][k] = wv.w;
      }
      const float* src = &sm[B_SP1 + ic*324 + rh*144 + c];
      #pragma unroll
      for (int rr = 0; rr < 10; ++rr) {
        const float i0 = src[rr*18], i1 = src[rr*18 + 1], i2 = src[rr*18 + 2];
        #pragma unroll
        for (int dr = 0; dr < 3; ++dr) {
          const int r = rr - dr;
          if (r < 0 || r > 7) continue;
          #pragma unroll
          for (int o = 0; o < 4; ++o) {
            acc[o][r] = fmaf(w[o][dr*3+0], i0, acc[o][r]);
            acc[o][r] = fmaf(w[o][dr*3+1], i1, acc[o][r]);
            acc[o][r] = fmaf(w[o][dr*3+2], i2, acc[o][r]);
          }
        }
      }
    }
    __syncthreads();
  }

  #pragma unroll
  for (int o = 0; o < 4; ++o) {
    const int ocl = 4*g + o;
    const float s = sm[B_BS + ocl], bo = sm[B_BB + ocl];
    float m[4];
    #pragma unroll
    for (int pr = 0; pr < 4; ++pr) {
      float v0 = fmaxf(fmaf(acc[o][2*pr],   s, bo), 0.f);
      float v1 = fmaxf(fmaf(acc[o][2*pr+1], s, bo), 0.f);
      m[pr] = fmaxf(v0, v1);
    }
    #pragma unroll
    for (int pr = 0; pr < 4; ++pr) {
      float nb = __shfl_xor(m[pr], 1);
      m[pr] = fmaxf(m[pr], nb);
    }
    if (!(c & 1)) {
      const int pc = c >> 1;
      #pragma unroll
      for (int pr = 0; pr < 4; ++pr)
        P2g[b*4096 + (oc0 + ocl)*64 + (rh*4 + pr)*8 + pc] = m[pr];
    }
  }
}

// ====== expert phase C: conv3 64->128 (8x8) + bn/relu + GAP -> featg =======
// grid 1024 = sample*4 + oc-quarter; 256 thr = g(8; 4oc) x (c=l&7, rh, h)
// h = ic-half split; combine via padded LDS exchange.
#define C_SP2 0       // [64][10][10] = 6400
#define C_WD  6400    // dbuf 2 x [2part][4icl][9][32oc] = 4608
#define C_BS  11008
#define C_BB  11040
__global__ __launch_bounds__(256) void expC_kernel(
    const int* __restrict__ chosen, const float* __restrict__ P2g,
    const float* __restrict__ ew3t, const float* __restrict__ eg3,
    const float* __restrict__ eb3, float* __restrict__ featg)
{
  __shared__ __align__(16) float sm[11072];
  const int t = threadIdx.x;
  const int b = blockIdx.x >> 2, ocq = blockIdx.x & 3, oc0 = 32*ocq;
  const int e = chosen[b];

  for (int j = t; j < 2304; j += 256) {
    int ic = j / 36, rem = j % 36, r, cxx;
    if (rem < 10)      { r = 0; cxx = rem; }
    else if (rem < 20) { r = 9; cxx = rem - 10; }
    else { int rr2 = rem - 20; r = 1 + (rr2 >> 1); cxx = (rr2 & 1) * 9; }
    sm[C_SP2 + ic*100 + r*10 + cxx] = 0.f;
  }
  const float4* P2g4 = (const float4*)P2g;
  for (int j = t; j < 1024; j += 256) {
    int ic = j >> 4, rem = j & 15, row = rem >> 1, cq = rem & 1;
    float4 v = P2g4[b*1024 + j];
    int base = C_SP2 + ic*100 + (row + 1)*10 + 1 + 4*cq;
    sm[base] = v.x; sm[base+1] = v.y; sm[base+2] = v.z; sm[base+3] = v.w;
  }
  if (t < 32) { sm[C_BS + t] = eg3[e*128 + oc0 + t]*BN_RS; sm[C_BB + t] = eb3[e*128 + oc0 + t]; }
  for (int j = t; j < 2304; j += 256) {           // chunk 0
    int part = j / 1152, r = j % 1152, icl = r / 288, r2 = r % 288;
    int k = r2 / 32, ocl = r2 & 31;
    sm[C_WD + j] = ew3t[e*73728 + (32*part + icl)*1152 + k*128 + oc0 + ocl];
  }
  __syncthreads();

  const int g = t >> 5, l = t & 31;
  const int c = l & 7, rh = (l >> 3) & 1, h = l >> 4;
  float acc[4][4];
  #pragma unroll
  for (int o = 0; o < 4; ++o)
    #pragma unroll
    for (int r = 0; r < 4; ++r) acc[o][r] = 0.f;

  for (int cc = 0; cc < 8; ++cc) {
    if (cc < 7) {
      for (int j = t; j < 2304; j += 256) {
        int part = j / 1152, r = j % 1152, icl = r / 288, r2 = r % 288;
        int k = r2 / 32, ocl = r2 & 31;
        sm[C_WD + ((cc+1)&1)*2304 + j] =
            ew3t[e*73728 + (32*part + 4*(cc+1) + icl)*1152 + k*128 + oc0 + ocl];
      }
    }
    const float* wb = &sm[C_WD + (cc & 1)*2304 + h*1152];
    #pragma unroll
    for (int icl = 0; icl < 4; ++icl) {
      const int ic = 32*h + 4*cc + icl;
      float w[4][9];
      #pragma unroll
      for (int k = 0; k < 9; ++k) {
        float4 wv = *(const float4*)&wb[icl*288 + k*32 + 4*g];
        w[0][k] = wv.x; w[1][k] = wv.y; w[2][k] = wv.z; w[3][k] = wv.w;
      }
      const float* src = &sm[C_SP2 + ic*100 + rh*40 + c];
      #pragma unroll
      for (int rr = 0; rr < 6; ++rr) {
        const float i0 = src[rr*10], i1 = src[rr*10 + 1], i2 = src[rr*10 + 2];
        #pragma unroll
        for (int dr = 0; dr < 3; ++dr) {
          const int r = rr - dr;
          if (r < 0 || r > 3) continue;
          #pragma unroll
          for (int o = 0; o < 4; ++o) {
            acc[o][r] = fmaf(w[o][dr*3+0], i0, acc[o][r]);
            acc[o][r] = fmaf(w[o][dr*3+1], i1, acc[o][r]);
            acc[o][r] = fmaf(w[o][dr*3+2], i2, acc[o][r]);
          }
        }
      }
    }
    __syncthreads();
  }

  // h-split exchange (sP2/weight regions dead), slot stride 17
  const int slot = g*16 + (l & 15);
  if (h == 1) {
    #pragma unroll
    for (int o = 0; o < 4; ++o)
      #pragma unroll
      for (int r = 0; r < 4; ++r)
        sm[slot*17 + o*4 + r] = acc[o][r];
  }
  __syncthreads();
  if (h == 0) {
    #pragma unroll
    for (int o = 0; o < 4; ++o) {
      const int ocl = 4*g + o;
      const float s = sm[C_BS + ocl], bo = sm[C_BB + ocl];
      float gsum = 0.f;
      #pragma unroll
      for (int r = 0; r < 4; ++r) {
        float v = acc[o][r] + sm[slot*17 + o*4 + r];
        gsum += fmaxf(fmaf(v, s, bo), 0.f);
      }
      gsum += __shfl_xor(gsum, 1);
      gsum += __shfl_xor(gsum, 2);
      gsum += __shfl_xor(gsum, 4);
      gsum += __shfl_xor(gsum, 8);
      if ((l & 15) == 0) featg[b*128 + oc0 + ocl] = gsum * (1.f/64.f);
    }
  }
}

// ================= expert phase D: FC chain -> final =======================
__global__ __launch_bounds__(128) void expD_kernel(
    const int* __restrict__ chosen, const float* __restrict__ featg,
    const float* __restrict__ efw, const float* __restrict__ efb,
    const float* __restrict__ cw1, const float* __restrict__ cb1,
    const float* __restrict__ cw2, const float* __restrict__ cb2,
    float* __restrict__ outF)
{
  __shared__ float sf[128], sff[128], sgg[64];
  const int b = blockIdx.x, t = threadIdx.x;
  const int e = chosen[b];
  sf[t] = featg[b*128 + t];
  __syncthreads();
  {
    float a = efb[e*128 + t];
    const float4* wp = (const float4*)&efw[e*16384 + t*128];
    #pragma unroll 8
    for (int i4 = 0; i4 < 32; ++i4) {
      float4 wv = wp[i4];
      a = fmaf(wv.x, sf[4*i4], a);   a = fmaf(wv.y, sf[4*i4+1], a);
      a = fmaf(wv.z, sf[4*i4+2], a); a = fmaf(wv.w, sf[4*i4+3], a);
    }
    sff[t] = fmaxf(a, 0.f);
  }
  __syncthreads();
  if (t < 64) {
    float a = cb1[e*64 + t];
    const float4* wp = (const float4*)&cw1[e*8192 + t*128];
    #pragma unroll 8
    for (int i4 = 0; i4 < 32; ++i4) {
      float4 wv = wp[i4];
      a = fmaf(wv.x, sff[4*i4], a);   a = fmaf(wv.y, sff[4*i4+1], a);
      a = fmaf(wv.z, sff[4*i4+2], a); a = fmaf(wv.w, sff[4*i4+3], a);
    }
    sgg[t] = fmaxf(a, 0.f);
  }
  __syncthreads();
  if (t < 10) {
    float a = cb2[e*10 + t];
    const float4* wp = (const float4*)&cw2[e*640 + t*64];
    #pragma unroll
    for (int i4 = 0; i4 < 16; ++i4) {
      float4 wv = wp[i4];
      a = fmaf(wv.x, sgg[4*i4], a);   a = fmaf(wv.y, sgg[4*i4+1], a);
      a = fmaf(wv.z, sgg[4*i4+2], a); a = fmaf(wv.w, sgg[4*i4+3], a);
    }
    outF[b*10 + t] = a;   // routing weight is exactly 1.0 for the chosen expert
  }
}

// ================================ host =====================================
extern "C" void kernel_launch(void* const* d_in, const int* in_sizes, int n_in,
                              void* d_out, int out_size, void* d_ws, size_t ws_size,
                              hipStream_t stream)
{
  const float* x   = (const float*)d_in[0];
  const float* tw1 = (const float*)d_in[1];
  const float* tg1 = (const float*)d_in[2];
  const float* tb1 = (const float*)d_in[3];
  const float* tw2 = (const float*)d_in[4];
  const float* tg2 = (const float*)d_in[5];
  const float* tb2 = (const float*)d_in[6];
  const float* tfw = (const float*)d_in[7];
  const float* tfb = (const float*)d_in[8];
  const float* gw1 = (const float*)d_in[9];
  const float* gb1 = (const float*)d_in[10];
  const float* gw2 = (const float*)d_in[11];
  const float* gb2 = (const float*)d_in[12];
  const float* ew1 = (const float*)d_in[13];
  const float* eg1 = (const float*)d_in[14];
  const float* eb1 = (const float*)d_in[15];
  const float* ew2 = (const float*)d_in[16];
  const float* eg2 = (const float*)d_in[17];
  const float* eb2 = (const float*)d_in[18];
  const float* ew3 = (const float*)d_in[19];
  const float* eg3 = (const float*)d_in[20];
  const float* eb3 = (const float*)d_in[21];
  const float* efw = (const float*)d_in[22];
  const float* efb = (const float*)d_in[23];
  const float* cw1 = (const float*)d_in[24];
  const float* cb1 = (const float*)d_in[25];
  const float* cw2 = (const float*)d_in[26];
  const float* cb2 = (const float*)d_in[27];

  float* out    = (float*)d_out;
  char*  ws     = (char*)d_ws;
  float* tf     = (float*)(ws + WS_TF);
  int*   tk     = (int*)(ws + WS_TK);
  int*   chosen = (int*)(ws + WS_CHOSEN);
  float* featg  = (float*)(ws + WS_FEATG);
  float* P1g    = (float*)(ws + WS_P1G);
  float* P2g    = (float*)(ws + WS_P2G);
  float* tw2t   = (float*)(ws + WS_TW2T);
  float* ew2t   = (float*)(ws + WS_EW2T);
  float* ew3t   = (float*)(ws + WS_EW3T);

  prep_kernel<<<2916, 256, 0, stream>>>(tw2, ew2, ew3, tw2t, ew2t, ew3t);
  trunk_kernel<<<1024, 256, 0, stream>>>(x, tw1, tg1, tb1, tw2t, tg2, tb2, tf);
  gate_kernel<<<256, 64, 0, stream>>>(tf, tfw, tfb, gw1, gb1, gw2, gb2, out + 2560, tk);
  route_kernel<<<1, 256, 0, stream>>>(tk, chosen, out + 4608);
  expA_kernel<<<1024, 256, 0, stream>>>(x, chosen, ew1, eg1, eb1, P1g);
  expB_kernel<<<512, 256, 0, stream>>>(chosen, P1g, ew2t, eg2, eb2, P2g);
  expC_kernel<<<1024, 256, 0, stream>>>(chosen, P2g, ew3t, eg3, eb3, featg);
  expD_kernel<<<256, 128, 0, stream>>>(chosen, featg, efw, efb, cw1, cb1, cw2, cb2, out);
}